// Round 10
// baseline (27274.234 us; speedup 1.0000x reference)
//
#include <hip/hip_runtime.h>
#include <math.h>

#define STT 512
#define SLL 64

typedef __bf16 v8bf __attribute__((ext_vector_type(8)));
typedef float f32x4 __attribute__((ext_vector_type(4)));

#define MFMA16(a, b, c) __builtin_amdgcn_mfma_f32_16x16x32_bf16(a, b, c, 0, 0, 0)

__device__ __forceinline__ float sigm(float x) { return 1.0f / (1.0f + __expf(-x)); }

// ---------------------------------------------------------------------------
// Layouts (all "frag" layouts are the exact per-lane MFMA operand order):
//  x/h B-frags : [t][blk 4][kt][term 2(hi,lo)][lane 64][8 bf16]
//                (B-frag: col=lane&15=batch-within-block, k=kt*32+(lane>>4)*8+e)
//  W A-frags   : [kt][wave 4][tile 16][term 2][lane 64][8 bf16]
//                (A-frag: row=lane&15 within tile, k same; tile j: gate=j&3,
//                 unit-chunk uc=wave*4+(j>>2), rows = gate*256+uc*16+(lane&15))
//  D (16x16)   : col=lane&15=batch, row=(lane>>4)*4+reg=unit-within-16  [m89]
// Batch-split: block = (stream s, blk) owns batches blk*16..+15, ALL units.
// => the LSTM recurrence is block-local: NO inter-block sync of any kind.
// ---------------------------------------------------------------------------

// x gather directly into B-frag layout, split-bf16.
__global__ __launch_bounds__(256) void gather_xfrag(const int* __restrict__ tok,
                                                    const float* __restrict__ emb,
                                                    __bf16* __restrict__ xf, int T) {
  int idx = blockIdx.x * 256 + threadIdx.x;  // ((t*4+blk)*8+kt)*64+lane
  int lane = idx & 63;
  int kt = (idx >> 6) & 7;
  int blk = (idx >> 9) & 3;
  int t = idx >> 11;
  if (t >= T) return;
  int b = blk * 16 + (lane & 15);
  int k0 = kt * 32 + (lane >> 4) * 8;
  int token = tok[b * T + t];
  const float* e = emb + (size_t)token * 256 + k0;
  v8bf hi, lo;
#pragma unroll
  for (int i = 0; i < 8; ++i) {
    float v = e[i];
    __bf16 h = (__bf16)v;
    hi[i] = h;
    lo[i] = (__bf16)(v - (float)h);
  }
  __bf16* dst = xf + (((size_t)t * 4 + blk) * 8192) + ((size_t)kt * 2 * 64 + lane) * 8;
  *(v8bf*)dst = hi;
  *(v8bf*)(dst + 512) = lo;
}

// ctx weights [Wih | Whh] (K=512) -> A-frag stream layout, split-bf16.
__global__ __launch_bounds__(256) void prep_w_ctx(const float* __restrict__ Wih,
                                                  const float* __restrict__ Whh,
                                                  __bf16* __restrict__ wf) {
  int idx = blockIdx.x * 256 + threadIdx.x;  // ((kt*4+wv)*16+tile)*64+lane
  int lane = idx & 63;
  int tile = (idx >> 6) & 15;
  int wv = (idx >> 10) & 3;
  int kt = idx >> 12;  // 0..15
  int g = tile & 3, uc = wv * 4 + (tile >> 2);
  int row = g * 256 + uc * 16 + (lane & 15);
  int k0 = kt * 32 + (lane >> 4) * 8;
  v8bf hi, lo;
#pragma unroll
  for (int i = 0; i < 8; ++i) {
    int k = k0 + i;
    float v = (k < 256) ? Wih[(size_t)row * 256 + k] : Whh[(size_t)row * 256 + (k - 256)];
    __bf16 h = (__bf16)v;
    hi[i] = h;
    lo[i] = (__bf16)(v - (float)h);
  }
  __bf16* dst = wf + ((((size_t)kt * 4 + wv) * 16 + tile) * 2) * 512 + (size_t)lane * 8;
  *(v8bf*)dst = hi;
  *(v8bf*)(dst + 512) = lo;
}

// agg Whh (K=256) -> A-frag stream layout.
__global__ __launch_bounds__(256) void prep_w_agg(const float* __restrict__ Whh,
                                                  __bf16* __restrict__ wf) {
  int idx = blockIdx.x * 256 + threadIdx.x;
  int lane = idx & 63;
  int tile = (idx >> 6) & 15;
  int wv = (idx >> 10) & 3;
  int kt = idx >> 12;  // 0..7
  int g = tile & 3, uc = wv * 4 + (tile >> 2);
  int row = g * 256 + uc * 16 + (lane & 15);
  int k0 = kt * 32 + (lane >> 4) * 8;
  v8bf hi, lo;
#pragma unroll
  for (int i = 0; i < 8; ++i) {
    float v = Whh[(size_t)row * 256 + k0 + i];
    __bf16 h = (__bf16)v;
    hi[i] = h;
    lo[i] = (__bf16)(v - (float)h);
  }
  __bf16* dst = wf + ((((size_t)kt * 4 + wv) * 16 + tile) * 2) * 512 + (size_t)lane * 8;
  *(v8bf*)dst = hi;
  *(v8bf*)(dst + 512) = lo;
}

struct CArgs {
  const __bf16* xf[4];  // x B-frags per stream
  const __bf16* wf[4];  // ctx A-frag weights per stream (K=512)
  const float* bih[4];
  const float* bhh[4];
  __bf16* hf[4];  // hs output, B-frag layout [t][blk][kt8][term2][lane][8]
  int T[4];
  int dir[4];
};

// ctx BiLSTM, batch-split: 16 blocks (s=blockIdx>>2, blk=blockIdx&3), 256 thr.
__global__ __launch_bounds__(256, 1) void ctx_persist(CArgs A) {
  const int s = blockIdx.x >> 2;
  const int blk = blockIdx.x & 3;
  const int T = A.T[s], dir = A.dir[s];
  const int tid = threadIdx.x, lane = tid & 63, w = tid >> 6;
  const int kg = lane >> 4, bl = lane & 15;

  __shared__ __bf16 xstage[2][8192];  // x B-frags for one step (16KB each)
  __shared__ __bf16 hload[2][8192];   // h B-frags (double-buffered)
  __shared__ float bias_s[1024];

  for (int i = tid; i < 1024; i += 256) bias_s[i] = A.bih[s][i] + A.bhh[s][i];

  float c[16];
#pragma unroll
  for (int j = 0; j < 16; ++j) c[j] = 0.f;

  // initial x tile (scan step 0)
  {
    int t0 = dir ? (T - 1) : 0;
    const __bf16* src = A.xf[s] + ((size_t)t0 * 4 + blk) * 8192;
    uint4 xv[4];
#pragma unroll
    for (int call = 0; call < 4; ++call)
      xv[call] = *(const uint4*)(src + call * 2048 + tid * 8);
#pragma unroll
    for (int call = 0; call < 4; ++call)
      *(uint4*)&xstage[0][call * 2048 + tid * 8] = xv[call];
  }
  __syncthreads();

  for (int t = 0; t < T; ++t) {
    const int xb = t & 1;

    // prefetch next x tile to regs (completes under MFMA/combine)
    uint4 xv[4];
    const bool pf = (t + 1 < T);
    if (pf) {
      int tn = dir ? (T - 2 - t) : (t + 1);
      const __bf16* src = A.xf[s] + ((size_t)tn * 4 + blk) * 8192;
#pragma unroll
      for (int call = 0; call < 4; ++call)
        xv[call] = *(const uint4*)(src + call * 2048 + tid * 8);
    }

    // export h_{t-1} (stable content of hload[t&1]) to global, coalesced
    if (t >= 1) {
      __bf16* dst = A.hf[s] + ((size_t)(t - 1) * 4 + blk) * 8192;
#pragma unroll
      for (int call = 0; call < 4; ++call) {
        uint4 v = *(const uint4*)&hload[t & 1][call * 2048 + tid * 8];
        *(uint4*)(dst + call * 2048 + tid * 8) = v;
      }
    }

    // ---- gate GEMM: D[unit][batch] += W[unit][k] * [x;h][batch][k] ----
    f32x4 acc[16];
#pragma unroll
    for (int j = 0; j < 16; ++j) acc[j] = (f32x4)(0.f);
    const int ktmax = t ? 16 : 8;  // h part (kt>=8) only when t>0
#pragma unroll 1
    for (int kt = 0; kt < ktmax; ++kt) {
      const __bf16* bsrc = (kt < 8) ? &xstage[xb][(size_t)kt * 1024]
                                    : &hload[t & 1][(size_t)(kt - 8) * 1024];
      v8bf bhi = *(const v8bf*)&bsrc[lane * 8];
      v8bf blo = *(const v8bf*)&bsrc[512 + lane * 8];
      const __bf16* wk = A.wf[s] + ((size_t)kt * 4 + w) * 16384 + (size_t)lane * 8;
#pragma unroll
      for (int j = 0; j < 16; ++j) {
        v8bf ahi = *(const v8bf*)&wk[(size_t)j * 1024];
        v8bf alo = *(const v8bf*)&wk[(size_t)j * 1024 + 512];
        acc[j] = MFMA16(ahi, bhi, acc[j]);
        acc[j] = MFMA16(alo, bhi, acc[j]);
        acc[j] = MFMA16(ahi, blo, acc[j]);
      }
    }

    // ---- combine: all 4 gates of each cell live in this thread ----
    __bf16* hl = &hload[(t + 1) & 1][0];
#pragma unroll
    for (int uc = 0; uc < 4; ++uc) {
#pragma unroll
      for (int r = 0; r < 4; ++r) {
        const int cell = uc * 4 + r;
        const int unit = (w * 4 + uc) * 16 + kg * 4 + r;
        float gi = acc[uc * 4 + 0][r] + bias_s[unit];
        float gf = acc[uc * 4 + 1][r] + bias_s[256 + unit];
        float gz = acc[uc * 4 + 2][r] + bias_s[512 + unit];
        float go = acc[uc * 4 + 3][r] + bias_s[768 + unit];
        float iv = sigm(gi), fv = sigm(gf), zv = tanhf(gz), ov = sigm(go);
        float cn = fv * c[cell] + iv * zv;
        c[cell] = cn;
        float hv = ov * tanhf(cn);
        __bf16 hh = (__bf16)hv;
        __bf16 hlo_ = (__bf16)(hv - (float)hh);
        const int kt_h = unit >> 5, kgk = (unit >> 3) & 3, e = unit & 7;
        const int ix = ((kt_h * 2) * 64 + kgk * 16 + bl) * 8 + e;
        hl[ix] = hh;
        hl[ix + 512] = hlo_;
      }
    }

    // write prefetched x into the other xstage buffer
    if (pf) {
#pragma unroll
      for (int call = 0; call < 4; ++call)
        *(uint4*)&xstage[xb ^ 1][call * 2048 + tid * 8] = xv[call];
    }
    __syncthreads();
  }

  // export h_{T-1}
  {
    __bf16* dst = A.hf[s] + ((size_t)(T - 1) * 4 + blk) * 8192;
#pragma unroll
    for (int call = 0; call < 4; ++call) {
      uint4 v = *(const uint4*)&hload[T & 1][call * 2048 + tid * 8];
      *(uint4*)(dst + call * 2048 + tid * 8) = v;
    }
  }
}

struct GArgs {
  const float* mv[4];
  const __bf16* wfa[4];  // agg Whh A-frags (K=256)
  const float* wih[4];   // agg Wih [row][2]
  const float* bih[4];
  const float* bhh[4];
  float* finals;  // [4][64][256] fp32
  int T[4];
  int dir[4];
};

// agg BiLSTM, batch-split: 16 blocks, mv input folded into combine.
__global__ __launch_bounds__(256, 1) void agg_persist(GArgs A) {
  const int s = blockIdx.x >> 2;
  const int blk = blockIdx.x & 3;
  const int T = A.T[s], dir = A.dir[s];
  const int tid = threadIdx.x, lane = tid & 63, w = tid >> 6;
  const int kg = lane >> 4, bl = lane & 15;

  __shared__ __bf16 hload[2][8192];
  __shared__ float bias_s[1024];
  __shared__ float w01_s[2048];  // [2][1024] gate-row-indexed

  for (int i = tid; i < 1024; i += 256) {
    bias_s[i] = A.bih[s][i] + A.bhh[s][i];
    w01_s[i] = A.wih[s][i * 2 + 0];
    w01_s[1024 + i] = A.wih[s][i * 2 + 1];
  }
  float c[16];
#pragma unroll
  for (int j = 0; j < 16; ++j) c[j] = 0.f;
  __syncthreads();

  const int gb = blk * 16 + bl;
  for (int t = 0; t < T; ++t) {
    f32x4 acc[16];
#pragma unroll
    for (int j = 0; j < 16; ++j) acc[j] = (f32x4)(0.f);
    if (t > 0) {
#pragma unroll 1
      for (int kt = 0; kt < 8; ++kt) {
        const __bf16* bsrc = &hload[t & 1][(size_t)kt * 1024];
        v8bf bhi = *(const v8bf*)&bsrc[lane * 8];
        v8bf blo = *(const v8bf*)&bsrc[512 + lane * 8];
        const __bf16* wk = A.wfa[s] + ((size_t)kt * 4 + w) * 16384 + (size_t)lane * 8;
#pragma unroll
        for (int j = 0; j < 16; ++j) {
          v8bf ahi = *(const v8bf*)&wk[(size_t)j * 1024];
          v8bf alo = *(const v8bf*)&wk[(size_t)j * 1024 + 512];
          acc[j] = MFMA16(ahi, bhi, acc[j]);
          acc[j] = MFMA16(alo, bhi, acc[j]);
          acc[j] = MFMA16(ahi, blo, acc[j]);
        }
      }
    }
    const int t_eff = dir ? (T - 1 - t) : t;
    const float m0 = A.mv[s][(size_t)t_eff * 128 + gb];
    const float m1 = A.mv[s][(size_t)t_eff * 128 + 64 + gb];
    __bf16* hl = &hload[(t + 1) & 1][0];
#pragma unroll
    for (int uc = 0; uc < 4; ++uc) {
#pragma unroll
      for (int r = 0; r < 4; ++r) {
        const int cell = uc * 4 + r;
        const int unit = (w * 4 + uc) * 16 + kg * 4 + r;
        float gi = acc[uc * 4 + 0][r] + bias_s[unit] + w01_s[unit] * m0 +
                   w01_s[1024 + unit] * m1;
        float gf = acc[uc * 4 + 1][r] + bias_s[256 + unit] + w01_s[256 + unit] * m0 +
                   w01_s[1024 + 256 + unit] * m1;
        float gz = acc[uc * 4 + 2][r] + bias_s[512 + unit] + w01_s[512 + unit] * m0 +
                   w01_s[1024 + 512 + unit] * m1;
        float go = acc[uc * 4 + 3][r] + bias_s[768 + unit] + w01_s[768 + unit] * m0 +
                   w01_s[1024 + 768 + unit] * m1;
        float iv = sigm(gi), fv = sigm(gf), zv = tanhf(gz), ov = sigm(go);
        float cn = fv * c[cell] + iv * zv;
        c[cell] = cn;
        float hv = ov * tanhf(cn);
        __bf16 hh = (__bf16)hv;
        __bf16 hlo_ = (__bf16)(hv - (float)hh);
        const int kt_h = unit >> 5, kgk = (unit >> 3) & 3, e = unit & 7;
        const int ix = ((kt_h * 2) * 64 + kgk * 16 + bl) * 8 + e;
        hl[ix] = hh;
        hl[ix + 512] = hlo_;
        if (t == T - 1) A.finals[((size_t)s * 64 + gb) * 256 + unit] = hv;
      }
    }
    __syncthreads();
  }
}

// mv from hfrag layout; v2 = broadcast final tile pointer.
__global__ __launch_bounds__(256) void mv_match2(
    const __bf16* __restrict__ hff, const __bf16* __restrict__ hfb,
    const __bf16* __restrict__ vff, const __bf16* __restrict__ vfb,
    const float* __restrict__ w1, const float* __restrict__ w2,
    float* __restrict__ mv, int T) {
  int idx = blockIdx.x * 256 + threadIdx.x;
  int b = idx & 63, t = idx >> 6;
  if (t >= T) return;
  int blk = b >> 4, bl = b & 15;
#pragma unroll 1
  for (int part = 0; part < 2; ++part) {
    const __bf16* p1 = (part == 0) ? hff + ((size_t)t * 4 + blk) * 8192
                                   : hfb + ((size_t)(T - 1 - t) * 4 + blk) * 8192;
    const __bf16* p2 = ((part == 0) ? vff : vfb) + (size_t)blk * 8192;
    const float* wv = (part == 0) ? w1 : w2;
    float num = 0.f, na = 0.f, nb = 0.f;
    for (int kt = 0; kt < 8; ++kt)
#pragma unroll
      for (int kgi = 0; kgi < 4; ++kgi) {
        int off = ((kt * 2) * 64 + kgi * 16 + bl) * 8;
        v8bf ah = *(const v8bf*)(p1 + off), al = *(const v8bf*)(p1 + off + 512);
        v8bf bh = *(const v8bf*)(p2 + off), blv = *(const v8bf*)(p2 + off + 512);
#pragma unroll
        for (int e = 0; e < 8; ++e) {
          int u = kt * 32 + kgi * 8 + e;
          float ww = wv[u];
          float av = ww * ((float)ah[e] + (float)al[e]);
          float bv = ww * ((float)bh[e] + (float)blv[e]);
          num = fmaf(av, bv, num);
          na = fmaf(av, av, na);
          nb = fmaf(bv, bv, nb);
        }
      }
    mv[((size_t)t * 2 + part) * 64 + b] = num / fmaxf(sqrtf(na) * sqrtf(nb), 1e-8f);
  }
}

// finals layout: [b][256]
__global__ __launch_bounds__(256) void final_fc(const float* __restrict__ pf,
                                                const float* __restrict__ pb,
                                                const float* __restrict__ hf,
                                                const float* __restrict__ hb,
                                                const float* __restrict__ fc1W,
                                                const float* __restrict__ fc1b,
                                                const float* __restrict__ fc2W,
                                                const float* __restrict__ fc2b,
                                                float* __restrict__ out) {
  __shared__ float xs[1024];
  __shared__ float ys[512];
  int b = blockIdx.x;
  for (int i = threadIdx.x; i < 1024; i += 256) {
    const float* src = (i < 256) ? pf : (i < 512) ? pb : (i < 768) ? hf : hb;
    xs[i] = src[(size_t)b * 256 + (i & 255)];
  }
  __syncthreads();
  for (int o = threadIdx.x; o < 512; o += 256) {
    float acc = fc1b[o];
    const float* w = fc1W + (size_t)o * 1024;
#pragma unroll 4
    for (int k = 0; k < 1024; ++k) acc = fmaf(w[k], xs[k], acc);
    ys[o] = tanhf(acc);
  }
  __syncthreads();
  if (threadIdx.x < 20) {
    int o = threadIdx.x;
    float acc = fc2b[o];
    const float* w = fc2W + (size_t)o * 512;
#pragma unroll 4
    for (int k = 0; k < 512; ++k) acc = fmaf(w[k], ys[k], acc);
    out[b * 20 + o] = acc;
  }
}

__global__ void guard_fill(float* out, int n, float v) {
  int i = blockIdx.x * 256 + threadIdx.x;
  if (i < n) out[i] = v;
}

extern "C" void kernel_launch(void* const* d_in, const int* in_sizes, int n_in,
                              void* d_out, int out_size, void* d_ws, size_t ws_size,
                              hipStream_t stream) {
  const int* text = (const int*)d_in[0];
  const int* label = (const int*)d_in[1];
  const float* emb = (const float*)d_in[2];
  const float* cWih_f = (const float*)d_in[3];
  const float* cWhh_f = (const float*)d_in[4];
  const float* cbih_f = (const float*)d_in[5];
  const float* cbhh_f = (const float*)d_in[6];
  const float* cWih_b = (const float*)d_in[7];
  const float* cWhh_b = (const float*)d_in[8];
  const float* cbih_b = (const float*)d_in[9];
  const float* cbhh_b = (const float*)d_in[10];
  const float* w1 = (const float*)d_in[11];
  const float* w2 = (const float*)d_in[12];
  const float* aWih_f = (const float*)d_in[13];
  const float* aWhh_f = (const float*)d_in[14];
  const float* abih_f = (const float*)d_in[15];
  const float* abhh_f = (const float*)d_in[16];
  const float* aWih_b = (const float*)d_in[17];
  const float* aWhh_b = (const float*)d_in[18];
  const float* abih_b = (const float*)d_in[19];
  const float* abhh_b = (const float*)d_in[20];
  const float* fc1W = (const float*)d_in[21];
  const float* fc1b = (const float*)d_in[22];
  const float* fc2W = (const float*)d_in[23];
  const float* fc2b = (const float*)d_in[24];
  float* out = (float*)d_out;

  char* base = (char*)d_ws;
  size_t off = 0;
  auto alloc = [&](size_t bytes) {
    void* p = base + off;
    off = (off + bytes + 255) & ~(size_t)255;
    return p;
  };

  const size_t TCH = 8192;  // bf16 per (t,blk) chunk
  __bf16* xf_p = (__bf16*)alloc((size_t)STT * 4 * TCH * 2);
  __bf16* xf_h = (__bf16*)alloc((size_t)SLL * 4 * TCH * 2);
  __bf16* wf_cf = (__bf16*)alloc((size_t)16 * 4 * 16 * 2 * 512 * 2);
  __bf16* wf_cb = (__bf16*)alloc((size_t)16 * 4 * 16 * 2 * 512 * 2);
  __bf16* wfa_f = (__bf16*)alloc((size_t)8 * 4 * 16 * 2 * 512 * 2);
  __bf16* wfa_b = (__bf16*)alloc((size_t)8 * 4 * 16 * 2 * 512 * 2);
  __bf16* hf_pf = (__bf16*)alloc((size_t)STT * 4 * TCH * 2);
  __bf16* hf_pb = (__bf16*)alloc((size_t)STT * 4 * TCH * 2);
  __bf16* hf_hf = (__bf16*)alloc((size_t)SLL * 4 * TCH * 2);
  __bf16* hf_hb = (__bf16*)alloc((size_t)SLL * 4 * TCH * 2);
  float* mv_p = (float*)alloc((size_t)STT * 128 * 4);
  float* mv_h = (float*)alloc((size_t)SLL * 128 * 4);
  float* finals = (float*)alloc((size_t)4 * 64 * 256 * 4);

  if (ws_size < off) {
    guard_fill<<<(out_size + 255) / 256, 256, 0, stream>>>(out, out_size,
                                                           (float)(ws_size >> 20));
    return;
  }

  gather_xfrag<<<(STT * 4 * 8 * 64) / 256, 256, 0, stream>>>(text, emb, xf_p, STT);
  gather_xfrag<<<(SLL * 4 * 8 * 64) / 256, 256, 0, stream>>>(label, emb, xf_h, SLL);
  prep_w_ctx<<<256, 256, 0, stream>>>(cWih_f, cWhh_f, wf_cf);
  prep_w_ctx<<<256, 256, 0, stream>>>(cWih_b, cWhh_b, wf_cb);
  prep_w_agg<<<128, 256, 0, stream>>>(aWhh_f, wfa_f);
  prep_w_agg<<<128, 256, 0, stream>>>(aWhh_b, wfa_b);

  CArgs cx;
  cx.xf[0] = xf_p; cx.xf[1] = xf_p; cx.xf[2] = xf_h; cx.xf[3] = xf_h;
  cx.wf[0] = wf_cf; cx.wf[1] = wf_cb; cx.wf[2] = wf_cf; cx.wf[3] = wf_cb;
  for (int s = 0; s < 4; ++s) {
    cx.bih[s] = (s & 1) ? cbih_b : cbih_f;
    cx.bhh[s] = (s & 1) ? cbhh_b : cbhh_f;
    cx.T[s] = (s < 2) ? STT : SLL;
    cx.dir[s] = s & 1;
  }
  cx.hf[0] = hf_pf; cx.hf[1] = hf_pb; cx.hf[2] = hf_hf; cx.hf[3] = hf_hb;
  ctx_persist<<<16, 256, 0, stream>>>(cx);

  // premise mv: fw vs hyp-fw-last (scan step SLL-1); bw vs hyp-bw t0 (scan SLL-1)
  mv_match2<<<(STT * 64) / 256, 256, 0, stream>>>(
      hf_pf, hf_pb, hf_hf + (size_t)(SLL - 1) * 4 * TCH,
      hf_hb + (size_t)(SLL - 1) * 4 * TCH, w1, w2, mv_p, STT);
  mv_match2<<<(SLL * 64) / 256, 256, 0, stream>>>(
      hf_hf, hf_hb, hf_pf + (size_t)(STT - 1) * 4 * TCH,
      hf_pb + (size_t)(STT - 1) * 4 * TCH, w1, w2, mv_h, SLL);

  GArgs ag;
  ag.mv[0] = mv_p; ag.mv[1] = mv_p; ag.mv[2] = mv_h; ag.mv[3] = mv_h;
  ag.wfa[0] = wfa_f; ag.wfa[1] = wfa_b; ag.wfa[2] = wfa_f; ag.wfa[3] = wfa_b;
  for (int s = 0; s < 4; ++s) {
    ag.wih[s] = (s & 1) ? aWih_b : aWih_f;
    ag.bih[s] = (s & 1) ? abih_b : abih_f;
    ag.bhh[s] = (s & 1) ? abhh_b : abhh_f;
    ag.T[s] = (s < 2) ? STT : SLL;
    ag.dir[s] = s & 1;
  }
  ag.finals = finals;
  agg_persist<<<16, 256, 0, stream>>>(ag);

  final_fc<<<64, 256, 0, stream>>>(finals + 0 * 64 * 256, finals + 1 * 64 * 256,
                                   finals + 2 * 64 * 256, finals + 3 * 64 * 256,
                                   fc1W, fc1b, fc2W, fc2b, out);
}